// Round 1
// baseline (180.277 us; speedup 1.0000x reference)
//
#include <hip/hip_runtime.h>
#include <math.h>

// Problem constants
#define CC   128         // channels
#define NL   16384       // N * H * W = 4*64*64
#define LHW  4096        // H*W
#define OMP  112         // padded om row stride (108 real cols)
#define HH   64
#define WW   64

typedef __attribute__((ext_vector_type(8))) short short8;
typedef __attribute__((ext_vector_type(4))) float f32x4;

__device__ __forceinline__ unsigned short f2bf(float f) {
    union { float f; unsigned u; } v; v.f = f;
    unsigned r = v.u + 0x7fff + ((v.u >> 16) & 1);   // RNE
    return (unsigned short)(r >> 16);
}
__device__ __forceinline__ float bf2f(unsigned short u) {
    union { unsigned u; float f; } v; v.u = ((unsigned)u) << 16;
    return v.f;
}

// ---------------------------------------------------------------------------
// Weight prep + stats zero + x -> xT (bf16 NHWC).
// Blocks 0..247: weights (Wcomb/WoT/Wcb) + stats zero.
// Blocks 248..503: xT[nl][128] bf16 transpose of x NCHW.
// ---------------------------------------------------------------------------
__global__ __launch_bounds__(256) void prep_kernel(
    const float* __restrict__ Wv, const float* __restrict__ Wom,
    const float* __restrict__ Wo, const float* __restrict__ Wc,
    const float* __restrict__ x,
    unsigned short* __restrict__ Wcomb, unsigned short* __restrict__ WoT,
    unsigned short* __restrict__ Wcb, unsigned short* __restrict__ xT,
    float* __restrict__ stats)
{
    int tid = threadIdx.x;
    int b = blockIdx.x;
    if (b < 248) {
        if (b == 0) {                        // zero 512 stats floats
            stats[tid] = 0.0f;
            stats[256 + tid] = 0.0f;
        }
        int i = b * 256 + tid;               // 63488 total
        if (i < 16384) {
            int n = i >> 7, k = i & 127;
            Wcomb[i] = f2bf(Wv[k * CC + n]);
        } else if (i < 30720) {
            int j = i - 16384; int n = j >> 7, k = j & 127;   // n in 0..111
            Wcomb[16384 + j] = (n < 108) ? f2bf(Wom[k * 108 + n]) : (unsigned short)0;
        } else if (i < 47104) {
            int j = i - 30720; int n = j >> 7, k = j & 127;
            WoT[j] = f2bf(Wo[k * CC + n]);
        } else if (i < 63488) {
            int j = i - 47104;
            Wcb[j] = f2bf(Wc[j]);
        }
    } else {
        __shared__ alignas(16) unsigned short As[64 * 136];
        int block_m = (b - 248) * 64;
        int n   = block_m >> 12;
        int hw0 = block_m & 4095;
#pragma unroll
        for (int i = 0; i < 8; i++) {
            int id = tid + i * 256;          // 0..2047
            int c  = id >> 4, j4 = id & 15;
            float4 v = *(const float4*)(x + (((size_t)(n * CC + c)) << 12) + hw0 + j4 * 4);
            As[(j4 * 4 + 0) * 136 + c] = f2bf(v.x);
            As[(j4 * 4 + 1) * 136 + c] = f2bf(v.y);
            As[(j4 * 4 + 2) * 136 + c] = f2bf(v.z);
            As[(j4 * 4 + 3) * 136 + c] = f2bf(v.w);
        }
        __syncthreads();
#pragma unroll
        for (int i = 0; i < 4; i++) {
            int id = tid + i * 256;          // 0..1023
            int r = id >> 4, kc = id & 15;
            *(float4*)(xT + (size_t)(block_m + r) * CC + kc * 8) =
                *(const float4*)(&As[r * 136 + kc * 8]);
        }
    }
}

// ---------------------------------------------------------------------------
// Fused value+om GEMM, LDS-free: [M=16384 x N=240 x K=128].
// Each wave: 16 rows x 80 cols (5 MFMA col-frags). 3072 waves = 768 blocks.
// A fragments loaded direct from global (xT bf16 in mode 0, bn_relu(ybuf)
// computed in-register in mode 1). B fragments streamed from L2 (Wcomb).
// No barriers in mode 0; one barrier for bn table in mode 1.
// ---------------------------------------------------------------------------
template<int IN_MODE>
__global__ __launch_bounds__(256, 3) void gemm_vom_kernel(
    const void* __restrict__ Ain_, const unsigned short* __restrict__ Wcomb,
    const float* __restrict__ bv, const float* __restrict__ bom,
    const float* __restrict__ stats, const float* __restrict__ gamma,
    const float* __restrict__ beta,
    unsigned short* __restrict__ val, float* __restrict__ omb)
{
    __shared__ alignas(16) float bnsc[128];
    __shared__ alignas(16) float bnsh[128];

    int tid = threadIdx.x;
    if (IN_MODE == 1) {
        if (tid < 128) {
            const float inv = 1.0f / 16384.0f;
            float mean = stats[tid] * inv;
            float var  = stats[128 + tid] * inv - mean * mean;
            float sc   = rsqrtf(var + 1e-5f) * gamma[tid];
            bnsc[tid] = sc;
            bnsh[tid] = beta[tid] - mean * sc;
        }
        __syncthreads();
    }

    int w  = tid >> 6;
    int l  = tid & 63;
    int lr = l & 15, lk = l >> 4;

    int wid = blockIdx.x * 4 + w;        // 0..3071
    int rt  = wid / 3;                   // row tile 0..1023
    int cc  = wid - rt * 3;              // col chunk 0..2
    int row = rt * 16 + lr;

    short8 a[4];
    if (IN_MODE == 0) {
        const unsigned short* ap = (const unsigned short*)Ain_ + (size_t)row * CC + lk * 8;
#pragma unroll
        for (int kk = 0; kk < 4; kk++)
            a[kk] = *(const short8*)(ap + kk * 32);
    } else {
        const float* ap = (const float*)Ain_ + (size_t)row * CC + lk * 8;
#pragma unroll
        for (int kk = 0; kk < 4; kk++) {
            float4 v0 = *(const float4*)(ap + kk * 32);
            float4 v1 = *(const float4*)(ap + kk * 32 + 4);
            int c = kk * 32 + lk * 8;
            float4 s0 = *(const float4*)(&bnsc[c]);
            float4 s1 = *(const float4*)(&bnsc[c + 4]);
            float4 h0 = *(const float4*)(&bnsh[c]);
            float4 h1 = *(const float4*)(&bnsh[c + 4]);
            short8 t;
            t[0] = (short)f2bf(fmaxf(v0.x * s0.x + h0.x, 0.0f));
            t[1] = (short)f2bf(fmaxf(v0.y * s0.y + h0.y, 0.0f));
            t[2] = (short)f2bf(fmaxf(v0.z * s0.z + h0.z, 0.0f));
            t[3] = (short)f2bf(fmaxf(v0.w * s0.w + h0.w, 0.0f));
            t[4] = (short)f2bf(fmaxf(v1.x * s1.x + h1.x, 0.0f));
            t[5] = (short)f2bf(fmaxf(v1.y * s1.y + h1.y, 0.0f));
            t[6] = (short)f2bf(fmaxf(v1.z * s1.z + h1.z, 0.0f));
            t[7] = (short)f2bf(fmaxf(v1.w * s1.w + h1.w, 0.0f));
            a[kk] = t;
        }
    }

    int F = cc * 5;                      // first col-frag (of 15)
    f32x4 acc[5];
#pragma unroll
    for (int f = 0; f < 5; f++) acc[f] = (f32x4){0.f, 0.f, 0.f, 0.f};

    const unsigned short* bp = Wcomb + (size_t)(F * 16 + lr) * CC + lk * 8;
#pragma unroll
    for (int f = 0; f < 5; f++) {
#pragma unroll
        for (int kk = 0; kk < 4; kk++) {
            short8 bfr = *(const short8*)(bp + f * 16 * CC + kk * 32);
            acc[f] = __builtin_amdgcn_mfma_f32_16x16x32_bf16(a[kk], bfr, acc[f], 0, 0, 0);
        }
    }

    int row0 = rt * 16 + lk * 4;
#pragma unroll
    for (int f = 0; f < 5; f++) {
        int frag = F + f;
        if (frag < 8) {                  // value output (bf16, +bv)
            int col = frag * 16 + lr;
            float bb = bv[col];
#pragma unroll
            for (int r = 0; r < 4; r++)
                val[(size_t)(row0 + r) * CC + col] = f2bf(acc[f][r] + bb);
        } else {                         // offset/mask output (fp32, +bom)
            int ocol = (frag - 8) * 16 + lr;     // 0..111
            float bb = (ocol < 108) ? bom[ocol] : 0.0f;
#pragma unroll
            for (int r = 0; r < 4; r++)
                omb[(size_t)(row0 + r) * OMP + ocol] = acc[f][r] + bb;
        }
    }
}

// ---------------------------------------------------------------------------
// Deformable sampling (bf16 value): 16 lanes per (nl,g) unit, 2 channels/lane.
// ---------------------------------------------------------------------------
__global__ __launch_bounds__(256) void sample_kernel(
    const unsigned short* __restrict__ val, const float* __restrict__ omb,
    unsigned int* __restrict__ sbuf)
{
    int tid    = threadIdx.x;
    int gid    = blockIdx.x * 256 + tid;
    int unit   = gid >> 4;                   // 65536 units
    int lane16 = gid & 15;
    int nl = unit >> 2;
    int g  = unit & 3;
    int n  = nl >> 12;
    int hw = nl & 4095;
    int h  = hw >> 6;
    int w  = hw & 63;

    const float* omp = omb + (size_t)nl * OMP + g * 27;
    const unsigned short* vb = val + (((size_t)n) << 19) + g * 32 + lane16 * 2;

    float acc0 = 0.0f, acc1 = 0.0f;
#pragma unroll
    for (int k = 0; k < 9; k++) {
        float ox = omp[2 * k];
        float oy = omp[2 * k + 1];
        float mk = omp[18 + k];
        float ly = (float)(h + k / 3 - 1) + oy;
        float lx = (float)(w + k % 3 - 1) + ox;
        float y0f = floorf(ly), x0f = floorf(lx);
        float wy = ly - y0f, wx = lx - x0f;
        int y0 = (int)y0f, x0 = (int)x0f;

        float v0 = 0.0f, v1 = 0.0f;
#pragma unroll
        for (int cy = 0; cy < 2; cy++) {
#pragma unroll
            for (int cx = 0; cx < 2; cx++) {
                int yi = y0 + cy, xi = x0 + cx;
                float wgt = (cy ? wy : 1.0f - wy) * (cx ? wx : 1.0f - wx);
                bool valid = (yi >= 0) && (yi < HH) && (xi >= 0) && (xi < WW);
                wgt = valid ? wgt : 0.0f;
                int yc = min(max(yi, 0), HH - 1);
                int xc = min(max(xi, 0), WW - 1);
                unsigned int pv = *(const unsigned int*)(vb + (size_t)(yc * WW + xc) * CC);
                v0 += bf2f((unsigned short)(pv & 0xffff)) * wgt;
                v1 += bf2f((unsigned short)(pv >> 16)) * wgt;
            }
        }
        acc0 += mk * v0;
        acc1 += mk * v1;
    }
    unsigned int packed = (unsigned int)f2bf(acc0) | ((unsigned int)f2bf(acc1) << 16);
    sbuf[(size_t)nl * 64 + g * 16 + lane16] = packed;
}

// ---------------------------------------------------------------------------
// Wo GEMM + fused BN-stats, LDS-free GEMM (LDS only for stat reduction).
// Each wave: 16 rows x 64 cols (4 frags). 2048 waves = 256 blocks x 8 waves.
// ---------------------------------------------------------------------------
__global__ __launch_bounds__(512, 2) void gemm_o_bn_kernel(
    const unsigned short* __restrict__ A, const unsigned short* __restrict__ Bt,
    float* __restrict__ ybuf, float* __restrict__ stats)
{
    __shared__ float lstat[256];

    int tid = threadIdx.x;
    if (tid < 256) lstat[tid] = 0.0f;
    __syncthreads();

    int w  = tid >> 6;
    int l  = tid & 63;
    int lr = l & 15, lk = l >> 4;

    int wid = blockIdx.x * 8 + w;        // 0..2047
    int rt  = wid >> 1;                  // row tile 0..1023
    int cc  = wid & 1;                   // col chunk 0..1
    int row = rt * 16 + lr;

    short8 a[4];
    const unsigned short* ap = A + (size_t)row * CC + lk * 8;
#pragma unroll
    for (int kk = 0; kk < 4; kk++)
        a[kk] = *(const short8*)(ap + kk * 32);

    f32x4 acc[4];
#pragma unroll
    for (int f = 0; f < 4; f++) acc[f] = (f32x4){0.f, 0.f, 0.f, 0.f};

    const unsigned short* bp = Bt + (size_t)(cc * 64 + lr) * CC + lk * 8;
#pragma unroll
    for (int f = 0; f < 4; f++) {
#pragma unroll
        for (int kk = 0; kk < 4; kk++) {
            short8 bfr = *(const short8*)(bp + f * 16 * CC + kk * 32);
            acc[f] = __builtin_amdgcn_mfma_f32_16x16x32_bf16(a[kk], bfr, acc[f], 0, 0, 0);
        }
    }

    int row0 = rt * 16 + lk * 4;
#pragma unroll
    for (int f = 0; f < 4; f++) {
        int col = cc * 64 + f * 16 + lr;
        float s = 0.0f, sq = 0.0f;
#pragma unroll
        for (int r = 0; r < 4; r++) {
            float v = acc[f][r];
            ybuf[(size_t)(row0 + r) * CC + col] = v;
            s += v;
            sq += v * v;
        }
        atomicAdd(&lstat[col], s);
        atomicAdd(&lstat[128 + col], sq);
    }
    __syncthreads();
    if (tid < 128) {
        atomicAdd(&stats[tid], lstat[tid]);
        atomicAdd(&stats[128 + tid], lstat[128 + tid]);
    }
}

// ---------------------------------------------------------------------------
// Final GEMM: A = bn(ybuf) + x_residual(NCHW), B = Wc; out NCHW fp32.
// ---------------------------------------------------------------------------
__global__ __launch_bounds__(256) void gemm_final_kernel(
    const float* __restrict__ ybuf, const float* __restrict__ x,
    const unsigned short* __restrict__ Bt, const float* __restrict__ stats,
    const float* __restrict__ gamma, const float* __restrict__ beta,
    float* __restrict__ out)
{
    __shared__ alignas(16) unsigned short As[64 * 136];
    __shared__ alignas(16) unsigned short Bs[128 * 136];
    __shared__ alignas(16) float Xs[64 * 132];
    __shared__ alignas(16) float bnsc[128];
    __shared__ alignas(16) float bnsh[128];

    int tid = threadIdx.x;
    int block_m = blockIdx.x * 64;
    int n   = block_m >> 12;
    int hw0 = block_m & 4095;

    if (tid < 128) {
        const float inv = 1.0f / 16384.0f;
        float mean = stats[tid] * inv;
        float var  = stats[128 + tid] * inv - mean * mean;
        float sc   = rsqrtf(var + 1e-5f) * gamma[tid];
        bnsc[tid] = sc;
        bnsh[tid] = beta[tid] - mean * sc;
    }

    // stage x residual (NCHW -> LDS transpose, fp32)
#pragma unroll
    for (int i = 0; i < 8; i++) {
        int id = tid + i * 256;
        int c  = id >> 4, j4 = id & 15;
        float4 v = *(const float4*)(x + (((size_t)(n * CC + c)) << 12) + hw0 + j4 * 4);
        Xs[(j4 * 4 + 0) * 132 + c] = v.x;
        Xs[(j4 * 4 + 1) * 132 + c] = v.y;
        Xs[(j4 * 4 + 2) * 132 + c] = v.z;
        Xs[(j4 * 4 + 3) * 132 + c] = v.w;
    }
    // stage B
#pragma unroll
    for (int i = 0; i < 8; i++) {
        int id = tid + i * 256;
        int r = id >> 4, kc = id & 15;
        float4 v = *(const float4*)(Bt + (size_t)r * CC + kc * 8);
        *(float4*)(&Bs[r * 136 + kc * 8]) = v;
    }
    __syncthreads();

    // stage A = bn(ybuf) + Xs
#pragma unroll
    for (int i = 0; i < 8; i++) {
        int id = tid + i * 256;
        int r  = id >> 5, c4 = id & 31;
        float4 v = *(const float4*)(ybuf + (size_t)(block_m + r) * CC + c4 * 4);
        int c = c4 * 4;
        float a0 = v.x * bnsc[c + 0] + bnsh[c + 0] + Xs[r * 132 + c + 0];
        float a1 = v.y * bnsc[c + 1] + bnsh[c + 1] + Xs[r * 132 + c + 1];
        float a2 = v.z * bnsc[c + 2] + bnsh[c + 2] + Xs[r * 132 + c + 2];
        float a3 = v.w * bnsc[c + 3] + bnsh[c + 3] + Xs[r * 132 + c + 3];
        As[r * 136 + c + 0] = f2bf(a0);
        As[r * 136 + c + 1] = f2bf(a1);
        As[r * 136 + c + 2] = f2bf(a2);
        As[r * 136 + c + 3] = f2bf(a3);
    }
    __syncthreads();

    int w  = tid >> 6;
    int l  = tid & 63;
    int wm = w & 1, wn = w >> 1;
    int lr = l & 15, lk = l >> 4;

    f32x4 acc[2][4];
#pragma unroll
    for (int mt = 0; mt < 2; mt++)
#pragma unroll
        for (int nt = 0; nt < 4; nt++) acc[mt][nt] = (f32x4){0.f, 0.f, 0.f, 0.f};

#pragma unroll
    for (int kk = 0; kk < 4; kk++) {
        short8 a[2], b[4];
#pragma unroll
        for (int mt = 0; mt < 2; mt++)
            a[mt] = *(const short8*)(&As[(wm * 32 + mt * 16 + lr) * 136 + kk * 32 + lk * 8]);
#pragma unroll
        for (int nt = 0; nt < 4; nt++)
            b[nt] = *(const short8*)(&Bs[(wn * 64 + nt * 16 + lr) * 136 + kk * 32 + lk * 8]);
#pragma unroll
        for (int mt = 0; mt < 2; mt++)
#pragma unroll
            for (int nt = 0; nt < 4; nt++)
                acc[mt][nt] = __builtin_amdgcn_mfma_f32_16x16x32_bf16(
                    a[mt], b[nt], acc[mt][nt], 0, 0, 0);
    }

    // NCHW scatter via LDS transpose (reuse Bs as float[128][68])
    __syncthreads();
    float* T = (float*)Bs;
#pragma unroll
    for (int mt = 0; mt < 2; mt++) {
        int rloc = wm * 32 + mt * 16 + lk * 4;
#pragma unroll
        for (int nt = 0; nt < 4; nt++) {
            int col = wn * 64 + nt * 16 + lr;
#pragma unroll
            for (int r = 0; r < 4; r++)
                T[col * 68 + rloc + r] = acc[mt][nt][r];
        }
    }
    __syncthreads();
    int o = tid >> 1, half = tid & 1;
    float* op = out + (((size_t)(n * CC + o)) << 12) + hw0 + half * 32;
#pragma unroll
    for (int i = 0; i < 8; i++) {
        float4 v = *(const float4*)(&T[o * 68 + half * 32 + i * 4]);
        *(float4*)(op + i * 4) = v;
    }
}

// ---------------------------------------------------------------------------
extern "C" void kernel_launch(void* const* d_in, const int* in_sizes, int n_in,
                              void* d_out, int out_size, void* d_ws, size_t ws_size,
                              hipStream_t stream)
{
    const float* x     = (const float*)d_in[0];
    const float* Wv    = (const float*)d_in[1];
    const float* bv    = (const float*)d_in[2];
    const float* Wom   = (const float*)d_in[3];
    const float* bom   = (const float*)d_in[4];
    const float* Wo    = (const float*)d_in[5];
    const float* gamma = (const float*)d_in[6];
    const float* beta  = (const float*)d_in[7];
    const float* Wc    = (const float*)d_in[8];
    float* out = (float*)d_out;

    char* ws = (char*)d_ws;
    unsigned short* val   = (unsigned short*)ws;   ws += (size_t)NL * CC * 2;    // 4 MB
    float*          omb   = (float*)ws;            ws += (size_t)NL * OMP * 4;   // 7.34 MB
    unsigned int*   sbuf  = (unsigned int*)ws;     ws += (size_t)NL * CC * 2;    // 4 MB
    float*          ybuf  = (float*)ws;            ws += (size_t)NL * CC * 4;    // 8 MB
    unsigned short* Wcomb = (unsigned short*)ws;   ws += 240 * 128 * 2;
    unsigned short* WoT   = (unsigned short*)ws;   ws += 128 * 128 * 2;
    unsigned short* Wcb   = (unsigned short*)ws;   ws += 128 * 128 * 2;
    float*          stats = (float*)ws;            ws += 2048;
    unsigned short* xT    = (unsigned short*)ws;   ws += (size_t)NL * CC * 2;    // 4 MB

    dim3 b256(256);
    dim3 b512(512);

    prep_kernel<<<504, b256, 0, stream>>>(Wv, Wom, Wo, Wc, x, Wcomb, WoT, Wcb, xT, stats);

    // ---- DCN block 1 ----
    gemm_vom_kernel<0><<<768, b256, 0, stream>>>(xT, Wcomb, bv, bom,
                                                 nullptr, nullptr, nullptr, val, omb);
    sample_kernel<<<4096, b256, 0, stream>>>(val, omb, sbuf);
    gemm_o_bn_kernel<<<256, b512, 0, stream>>>((const unsigned short*)sbuf, WoT, ybuf, stats);

    // ---- DCN block 2 (bn+relu fused into A-load) ----
    gemm_vom_kernel<1><<<768, b256, 0, stream>>>(ybuf, Wcomb, bv, bom,
                                                 stats, gamma, beta, val, omb);
    sample_kernel<<<4096, b256, 0, stream>>>(val, omb, sbuf);
    gemm_o_bn_kernel<<<256, b512, 0, stream>>>((const unsigned short*)sbuf, WoT, ybuf, stats + 256);

    // ---- final: bn2 + residual + 1x1 conv, NCHW out ----
    gemm_final_kernel<<<256, b256, 0, stream>>>(ybuf, x, Wcb, stats + 256, gamma, beta, out);
}